// Round 3
// baseline (927.809 us; speedup 1.0000x reference)
//
#include <hip/hip_runtime.h>
#include <stdint.h>

// K-means cluster aggregator, round 3: f16 MFMA scores + counting-sort aggregation.
//   scores: s[k,i] = ||c_k||^2 - 2 * <c_k, x_i>   (node_sq shift irrelevant to argmin)
//   Tie-break: packed (orderable_score<<32 | k) min -> smallest k on bit-equal scores;
//   duplicate centers have identical f16 rows + identical fp32 csq -> bit-identical scores.
//   Aggregation: histogram -> scan -> index scatter -> per-cluster coalesced gather-sum.

typedef _Float16 f16x8 __attribute__((ext_vector_type(8)));
typedef float    f32x4 __attribute__((ext_vector_type(4)));

#define DD 512   // feature dim (fixed by problem)
#define KK 1024  // clusters (fixed by problem)

static __device__ __forceinline__ unsigned orderable(float s) {
    unsigned u = __float_as_uint(s);
    return (u & 0x80000000u) ? ~u : (u | 0x80000000u);
}

// ---- kernel 1: gather centers -> f16 rows in ws + fp32 ||c||^2 -----------------
__global__ void gather_centers(const float* __restrict__ nodes,
                               const int* __restrict__ center_ind,
                               _Float16* __restrict__ cent16,   // [K][DD]
                               float* __restrict__ cent_sq,     // [K]
                               int K) {
    int k    = (int)blockIdx.x;
    int lane = (int)threadIdx.x;                 // 64
    int ci   = center_ind[k];
    const f32x4* p = reinterpret_cast<const f32x4*>(nodes + (size_t)ci * DD + lane * 8);
    f32x4 v0 = p[0], v1 = p[1];
    f16x8 h;
    h[0]=(_Float16)v0[0]; h[1]=(_Float16)v0[1]; h[2]=(_Float16)v0[2]; h[3]=(_Float16)v0[3];
    h[4]=(_Float16)v1[0]; h[5]=(_Float16)v1[1]; h[6]=(_Float16)v1[2]; h[7]=(_Float16)v1[3];
    *reinterpret_cast<f16x8*>(cent16 + (size_t)k * DD + lane * 8) = h;
    float ssq = v0[0]*v0[0]+v0[1]*v0[1]+v0[2]*v0[2]+v0[3]*v0[3]
              + v1[0]*v1[0]+v1[1]*v1[1]+v1[2]*v1[2]+v1[3]*v1[3];
    #pragma unroll
    for (int off = 32; off > 0; off >>= 1) ssq += __shfl_xor(ssq, off, 64);
    if (lane == 0) cent_sq[k] = ssq;             // same reduce order for every k ->
                                                 // duplicate ci gives bit-identical csq
}

// ---- kernel 2: MFMA assign + histogram --------------------------------------------
// block: 64 nodes, 256 threads (4 waves); wave w owns centers [w*K/4, (w+1)*K/4).
__launch_bounds__(256, 2)
__global__ void assign_mfma(const float* __restrict__ nodes,
                            const _Float16* __restrict__ cent16,  // [K][DD]
                            const float* __restrict__ cent_sq,    // [K]
                            unsigned* __restrict__ assignment,    // [N]
                            unsigned* __restrict__ counts,        // [K], pre-zeroed
                            int N, int K) {
    __shared__ __align__(16) _Float16 nt[64 * DD];       // 64 KB, XOR-swizzled
    __shared__ float csq[KK];
    __shared__ unsigned long long best[64];

    const int tid = (int)threadIdx.x;
    const int n0  = (int)blockIdx.x * 64;

    // stage node tile -> f16 LDS (once per block). f = it*256+tid: row = f>>6
    // (uniform per wave), dchunk = f&63 -> conflict-free swizzled writes.
    #pragma unroll
    for (int it = 0; it < 16; ++it) {
        int f   = it * 256 + tid;
        int row = f >> 6;
        int d0  = (f & 63) << 3;
        f32x4 v0 = {0.f,0.f,0.f,0.f}, v1 = {0.f,0.f,0.f,0.f};
        if (n0 + row < N) {
            const f32x4* p = reinterpret_cast<const f32x4*>(nodes + (size_t)(n0 + row) * DD + d0);
            v0 = p[0]; v1 = p[1];
        }
        f16x8 h;
        h[0]=(_Float16)v0[0]; h[1]=(_Float16)v0[1]; h[2]=(_Float16)v0[2]; h[3]=(_Float16)v0[3];
        h[4]=(_Float16)v1[0]; h[5]=(_Float16)v1[1]; h[6]=(_Float16)v1[2]; h[7]=(_Float16)v1[3];
        int byte = ((row << 10) + (d0 << 1)) ^ ((row & 7) << 4);
        *reinterpret_cast<f16x8*>(reinterpret_cast<char*>(nt) + byte) = h;
    }
    for (int j = tid; j < K;  j += 256) csq[j]  = cent_sq[j];
    for (int j = tid; j < 64; j += 256) best[j] = ~0ULL;
    __syncthreads();

    const int lane = tid & 63;
    const int wid  = tid >> 6;
    const int l15  = lane & 15;
    const int g    = lane >> 4;          // quarter group (k-slice / C-row group)
    const int g8   = g * 8;
    const int swz  = (l15 & 7) << 4;     // row&7 == l15&7 (rows are nG*16 + l15)
    const int cPerWave = K >> 2;
    const int cw0  = wid * cPerWave;
    char* ntb = reinterpret_cast<char*>(nt);

    int bbase[4];
    #pragma unroll
    for (int nG = 0; nG < 4; ++nG) bbase[nG] = (((nG * 16 + l15) << 10) + (g << 4));

    const int nT = cPerWave >> 6;        // 64-center tiles per wave
    for (int t64 = 0; t64 < nT; ++t64) {
        const int cbase = cw0 + t64 * 64;
        f32x4 acc[4][4];                 // [center subtile][node group]
        #pragma unroll
        for (int a = 0; a < 4; ++a)
            #pragma unroll
            for (int b = 0; b < 4; ++b) { f32x4 z = {0.f,0.f,0.f,0.f}; acc[a][b] = z; }

        #pragma unroll 2
        for (int d0 = 0; d0 < DD; d0 += 32) {
            f16x8 A[4], B[4];
            #pragma unroll
            for (int tC = 0; tC < 4; ++tC)   // A: lane l -> row l&15, k = g*8+j (contig 16B)
                A[tC] = *reinterpret_cast<const f16x8*>(
                    cent16 + ((size_t)(cbase + tC * 16 + l15) << 9) + d0 + g8);
            #pragma unroll
            for (int nG = 0; nG < 4; ++nG)   // B: lane l -> col l&15, k = g*8+j (swizzled LDS)
                B[nG] = *reinterpret_cast<const f16x8*>(
                    ntb + ((bbase[nG] + (d0 << 1)) ^ swz));
            #pragma unroll
            for (int tC = 0; tC < 4; ++tC)
                #pragma unroll
                for (int nG = 0; nG < 4; ++nG)
                    acc[tC][nG] = __builtin_amdgcn_mfma_f32_16x16x32_f16(
                        A[tC], B[nG], acc[tC][nG], 0, 0, 0);
        }

        // epilogue: score = csq - 2*dot; packed min (smallest k on ties)
        #pragma unroll
        for (int nG = 0; nG < 4; ++nG) {
            unsigned long long pk = ~0ULL;
            #pragma unroll
            for (int tC = 0; tC < 4; ++tC) {
                #pragma unroll
                for (int q = 0; q < 4; ++q) {
                    int c = cbase + tC * 16 + g * 4 + q;   // C-row = g*4+q
                    float s = fmaf(-2.f, acc[tC][nG][q], csq[c]);
                    unsigned long long v =
                        ((unsigned long long)orderable(s) << 32) | (unsigned)c;
                    pk = v < pk ? v : pk;
                }
            }
            unsigned long long o;
            o = __shfl_xor(pk, 16, 64); pk = o < pk ? o : pk;
            o = __shfl_xor(pk, 32, 64); pk = o < pk ? o : pk;
            if (lane < 16) atomicMin(&best[nG * 16 + l15], pk);
        }
    }
    __syncthreads();
    if (tid < 64 && n0 + tid < N) {
        unsigned k = (unsigned)(best[tid] & 0xffffffffu);
        assignment[n0 + tid] = k;
        atomicAdd(&counts[k], 1u);
    }
}

// ---- kernel 3: exclusive scan of counts -> offsets (+cursor copy) -----------------
__global__ void scan_offsets(const unsigned* __restrict__ counts,
                             unsigned* __restrict__ offsets,
                             unsigned* __restrict__ cursor) {
    __shared__ unsigned s[KK];
    int t = (int)threadIdx.x;            // 1024
    unsigned c = counts[t];
    s[t] = c;
    __syncthreads();
    for (int off = 1; off < KK; off <<= 1) {
        unsigned v = (t >= off) ? s[t - off] : 0u;
        __syncthreads();
        s[t] += v;
        __syncthreads();
    }
    unsigned excl = s[t] - c;
    offsets[t] = excl;
    cursor[t]  = excl;
}

// ---- kernel 4: scatter node indices into per-cluster contiguous slices ------------
__global__ void scatter_idx(const unsigned* __restrict__ assignment,
                            unsigned* __restrict__ cursor,
                            unsigned* __restrict__ idx, int N) {
    int i = (int)(blockIdx.x * blockDim.x + threadIdx.x);
    if (i < N) {
        unsigned k = assignment[i];
        unsigned slot = atomicAdd(&cursor[k], 1u);
        idx[slot] = (unsigned)i;
    }
}

// ---- kernel 5: per-cluster coalesced gather-sum (no scan, no atomics) -------------
__launch_bounds__(256, 4)
__global__ void aggregate2(const float* __restrict__ nodes,
                           const unsigned* __restrict__ idx,
                           const unsigned* __restrict__ offsets,
                           const unsigned* __restrict__ counts,
                           float* __restrict__ out) {
    const int k    = (int)blockIdx.x;
    const int tid  = (int)threadIdx.x;
    const int wid  = tid >> 6;
    const int lane = tid & 63;
    const unsigned off = offsets[k];
    const int      cnt = (int)counts[k];

    f32x4 a0 = {0.f,0.f,0.f,0.f}, a1 = {0.f,0.f,0.f,0.f};   // dims lane*8 .. lane*8+7
    int j = wid;                                            // waves stride by 4
    for (; j + 4 < cnt; j += 8) {                           // 2-way unroll for MLP
        int i0 = (int)idx[off + j];
        int i1 = (int)idx[off + j + 4];
        const f32x4* p0 = reinterpret_cast<const f32x4*>(nodes + (size_t)i0 * DD + lane * 8);
        const f32x4* p1 = reinterpret_cast<const f32x4*>(nodes + (size_t)i1 * DD + lane * 8);
        f32x4 u0 = p0[0], u1 = p0[1], w0 = p1[0], w1 = p1[1];
        a0 += u0; a1 += u1;
        a0 += w0; a1 += w1;
    }
    if (j < cnt) {
        int i0 = (int)idx[off + j];
        const f32x4* p0 = reinterpret_cast<const f32x4*>(nodes + (size_t)i0 * DD + lane * 8);
        a0 += p0[0]; a1 += p0[1];
    }

    __shared__ float sums[4][DD];
    *reinterpret_cast<f32x4*>(&sums[wid][lane * 8])     = a0;
    *reinterpret_cast<f32x4*>(&sums[wid][lane * 8 + 4]) = a1;
    __syncthreads();
    for (int d = tid; d < DD; d += 256)
        out[(size_t)k * DD + d] = (sums[0][d] + sums[1][d]) + (sums[2][d] + sums[3][d]);
}

extern "C" void kernel_launch(void* const* d_in, const int* in_sizes, int n_in,
                              void* d_out, int out_size, void* d_ws, size_t ws_size,
                              hipStream_t stream) {
    const float* nodes      = (const float*)d_in[0];
    const int*   center_ind = (const int*)d_in[1];
    int K = in_sizes[1];                  // 1024
    int D = out_size / K;                 // 512 (DD)
    int N = in_sizes[0] / D;              // 100000
    (void)D;

    char* ws = (char*)d_ws;
    _Float16* cent16     = (_Float16*)ws;                          // K*DD*2 = 1 MB
    size_t    o          = (size_t)K * DD * 2;
    float*    cent_sq    = (float*)(ws + o);    o += (size_t)K * 4;
    unsigned* assignment = (unsigned*)(ws + o); o += (size_t)N * 4;
    unsigned* counts     = (unsigned*)(ws + o); o += (size_t)K * 4;
    unsigned* offsets    = (unsigned*)(ws + o); o += (size_t)K * 4;
    unsigned* cursor     = (unsigned*)(ws + o); o += (size_t)K * 4;
    unsigned* idx        = (unsigned*)(ws + o); o += (size_t)N * 4;
    float*    out        = (float*)d_out;

    hipMemsetAsync(counts, 0, (size_t)K * sizeof(unsigned), stream);

    gather_centers<<<K, 64, 0, stream>>>(nodes, center_ind, cent16, cent_sq, K);
    assign_mfma<<<(N + 63) / 64, 256, 0, stream>>>(nodes, cent16, cent_sq,
                                                   assignment, counts, N, K);
    scan_offsets<<<1, KK, 0, stream>>>(counts, offsets, cursor);
    scatter_idx<<<(N + 255) / 256, 256, 0, stream>>>(assignment, cursor, idx, N);
    aggregate2<<<K, 256, 0, stream>>>(nodes, idx, offsets, counts, out);
}

// Round 4
// 543.933 us; speedup vs baseline: 1.7057x; 1.7057x over previous
//
#include <hip/hip_runtime.h>
#include <stdint.h>

// K-means cluster aggregator, round 4: f16 MFMA scores + counting-sort +
// balanced segmented-reduction aggregation.
//   scores: s[k,i] = ||c_k||^2 - 2 * <c_k, x_i>   (node_sq shift irrelevant to argmin)
//   Tie-break: packed (orderable_score<<32 | k) min -> smallest k on bit-equal scores;
//   duplicate centers have identical f16 rows + identical fp32 csq -> bit-identical scores.
//   Aggregation: histogram -> scan -> packed-key scatter -> fixed-chunk segmented
//   reduction (balanced across waves; atomicAdd flush at segment boundaries only).

typedef _Float16 f16x8 __attribute__((ext_vector_type(8)));
typedef float    f32x4 __attribute__((ext_vector_type(4)));

#define DD 512   // feature dim (fixed by problem)
#define KK 1024  // clusters (fixed by problem)

static __device__ __forceinline__ unsigned orderable(float s) {
    unsigned u = __float_as_uint(s);
    return (u & 0x80000000u) ? ~u : (u | 0x80000000u);
}

// ---- kernel 1: gather centers -> f16 rows in ws + fp32 ||c||^2 -----------------
__global__ void gather_centers(const float* __restrict__ nodes,
                               const int* __restrict__ center_ind,
                               _Float16* __restrict__ cent16,   // [K][DD]
                               float* __restrict__ cent_sq,     // [K]
                               int K) {
    int k    = (int)blockIdx.x;
    int lane = (int)threadIdx.x;                 // 64
    int ci   = center_ind[k];
    const f32x4* p = reinterpret_cast<const f32x4*>(nodes + (size_t)ci * DD + lane * 8);
    f32x4 v0 = p[0], v1 = p[1];
    f16x8 h;
    h[0]=(_Float16)v0[0]; h[1]=(_Float16)v0[1]; h[2]=(_Float16)v0[2]; h[3]=(_Float16)v0[3];
    h[4]=(_Float16)v1[0]; h[5]=(_Float16)v1[1]; h[6]=(_Float16)v1[2]; h[7]=(_Float16)v1[3];
    *reinterpret_cast<f16x8*>(cent16 + (size_t)k * DD + lane * 8) = h;
    float ssq = v0[0]*v0[0]+v0[1]*v0[1]+v0[2]*v0[2]+v0[3]*v0[3]
              + v1[0]*v1[0]+v1[1]*v1[1]+v1[2]*v1[2]+v1[3]*v1[3];
    #pragma unroll
    for (int off = 32; off > 0; off >>= 1) ssq += __shfl_xor(ssq, off, 64);
    if (lane == 0) cent_sq[k] = ssq;             // same reduce order for every k ->
                                                 // duplicate ci gives bit-identical csq
}

// ---- kernel 2: MFMA assign + histogram --------------------------------------------
// block: 64 nodes, 256 threads (4 waves); wave w owns centers [w*K/4, (w+1)*K/4).
__launch_bounds__(256, 2)
__global__ void assign_mfma(const float* __restrict__ nodes,
                            const _Float16* __restrict__ cent16,  // [K][DD]
                            const float* __restrict__ cent_sq,    // [K]
                            unsigned* __restrict__ assignment,    // [N]
                            unsigned* __restrict__ counts,        // [K], pre-zeroed
                            int N, int K) {
    __shared__ __align__(16) _Float16 nt[64 * DD];       // 64 KB, XOR-swizzled
    __shared__ float csq[KK];
    __shared__ unsigned long long best[64];

    const int tid = (int)threadIdx.x;
    const int n0  = (int)blockIdx.x * 64;

    // stage node tile -> f16 LDS (once per block). f = it*256+tid: row = f>>6
    // (uniform per wave), dchunk = f&63 -> conflict-free swizzled writes.
    #pragma unroll
    for (int it = 0; it < 16; ++it) {
        int f   = it * 256 + tid;
        int row = f >> 6;
        int d0  = (f & 63) << 3;
        f32x4 v0 = {0.f,0.f,0.f,0.f}, v1 = {0.f,0.f,0.f,0.f};
        if (n0 + row < N) {
            const f32x4* p = reinterpret_cast<const f32x4*>(nodes + (size_t)(n0 + row) * DD + d0);
            v0 = p[0]; v1 = p[1];
        }
        f16x8 h;
        h[0]=(_Float16)v0[0]; h[1]=(_Float16)v0[1]; h[2]=(_Float16)v0[2]; h[3]=(_Float16)v0[3];
        h[4]=(_Float16)v1[0]; h[5]=(_Float16)v1[1]; h[6]=(_Float16)v1[2]; h[7]=(_Float16)v1[3];
        int byte = ((row << 10) + (d0 << 1)) ^ ((row & 7) << 4);
        *reinterpret_cast<f16x8*>(reinterpret_cast<char*>(nt) + byte) = h;
    }
    for (int j = tid; j < K;  j += 256) csq[j]  = cent_sq[j];
    for (int j = tid; j < 64; j += 256) best[j] = ~0ULL;
    __syncthreads();

    const int lane = tid & 63;
    const int wid  = tid >> 6;
    const int l15  = lane & 15;
    const int g    = lane >> 4;          // quarter group (k-slice / C-row group)
    const int g8   = g * 8;
    const int swz  = (l15 & 7) << 4;     // row&7 == l15&7 (rows are nG*16 + l15)
    const int cPerWave = K >> 2;
    const int cw0  = wid * cPerWave;
    char* ntb = reinterpret_cast<char*>(nt);

    int bbase[4];
    #pragma unroll
    for (int nG = 0; nG < 4; ++nG) bbase[nG] = (((nG * 16 + l15) << 10) + (g << 4));

    const int nT = cPerWave >> 6;        // 64-center tiles per wave
    for (int t64 = 0; t64 < nT; ++t64) {
        const int cbase = cw0 + t64 * 64;
        f32x4 acc[4][4];                 // [center subtile][node group]
        #pragma unroll
        for (int a = 0; a < 4; ++a)
            #pragma unroll
            for (int b = 0; b < 4; ++b) { f32x4 z = {0.f,0.f,0.f,0.f}; acc[a][b] = z; }

        #pragma unroll 2
        for (int d0 = 0; d0 < DD; d0 += 32) {
            f16x8 A[4], B[4];
            #pragma unroll
            for (int tC = 0; tC < 4; ++tC)   // A: lane l -> row l&15, k = g*8+j (contig 16B)
                A[tC] = *reinterpret_cast<const f16x8*>(
                    cent16 + ((size_t)(cbase + tC * 16 + l15) << 9) + d0 + g8);
            #pragma unroll
            for (int nG = 0; nG < 4; ++nG)   // B: lane l -> col l&15, k = g*8+j (swizzled LDS)
                B[nG] = *reinterpret_cast<const f16x8*>(
                    ntb + ((bbase[nG] + (d0 << 1)) ^ swz));
            #pragma unroll
            for (int tC = 0; tC < 4; ++tC)
                #pragma unroll
                for (int nG = 0; nG < 4; ++nG)
                    acc[tC][nG] = __builtin_amdgcn_mfma_f32_16x16x32_f16(
                        A[tC], B[nG], acc[tC][nG], 0, 0, 0);
        }

        // epilogue: score = csq - 2*dot; packed min (smallest k on ties)
        #pragma unroll
        for (int nG = 0; nG < 4; ++nG) {
            unsigned long long pk = ~0ULL;
            #pragma unroll
            for (int tC = 0; tC < 4; ++tC) {
                #pragma unroll
                for (int q = 0; q < 4; ++q) {
                    int c = cbase + tC * 16 + g * 4 + q;   // C-row = g*4+q
                    float s = fmaf(-2.f, acc[tC][nG][q], csq[c]);
                    unsigned long long v =
                        ((unsigned long long)orderable(s) << 32) | (unsigned)c;
                    pk = v < pk ? v : pk;
                }
            }
            unsigned long long o;
            o = __shfl_xor(pk, 16, 64); pk = o < pk ? o : pk;
            o = __shfl_xor(pk, 32, 64); pk = o < pk ? o : pk;
            if (lane < 16) atomicMin(&best[nG * 16 + l15], pk);
        }
    }
    __syncthreads();
    if (tid < 64 && n0 + tid < N) {
        unsigned k = (unsigned)(best[tid] & 0xffffffffu);
        assignment[n0 + tid] = k;
        atomicAdd(&counts[k], 1u);
    }
}

// ---- kernel 3: exclusive scan of counts -> cursor ---------------------------------
__global__ void scan_offsets(const unsigned* __restrict__ counts,
                             unsigned* __restrict__ cursor) {
    __shared__ unsigned s[KK];
    int t = (int)threadIdx.x;            // 1024
    unsigned c = counts[t];
    s[t] = c;
    __syncthreads();
    for (int off = 1; off < KK; off <<= 1) {
        unsigned v = (t >= off) ? s[t - off] : 0u;
        __syncthreads();
        s[t] += v;
        __syncthreads();
    }
    cursor[t] = s[t] - c;                // exclusive
}

// ---- kernel 4: scatter packed (k<<20 | node) keys into sorted slots ---------------
__global__ void scatter_idx(const unsigned* __restrict__ assignment,
                            unsigned* __restrict__ cursor,
                            unsigned* __restrict__ keys, int N) {
    int i = (int)(blockIdx.x * blockDim.x + threadIdx.x);
    if (i < N) {
        unsigned k = assignment[i];
        unsigned slot = atomicAdd(&cursor[k], 1u);
        keys[slot] = (k << 20) | (unsigned)i;   // N < 2^20, K < 2^10
    }
}

// ---- kernel 5: balanced segmented reduction over sorted slots ---------------------
// Each wave owns a fixed 32-slot chunk; flush to out via atomicAdd only at
// cluster-boundary / chunk-end. out must be pre-zeroed.
#define CHUNK 32
__launch_bounds__(256, 4)
__global__ void aggregate3(const float* __restrict__ nodes,
                           const unsigned* __restrict__ keys,   // [N] packed
                           float* __restrict__ out, int N) {
    const int tid  = (int)threadIdx.x;
    const int wid  = tid >> 6;
    const int lane = tid & 63;
    const int base = ((int)blockIdx.x * 4 + wid) * CHUNK;
    if (base >= N) return;
    const int n    = min(CHUNK, N - base);

    // lane j (j<32) caches key[base+j]; queried via shfl in the walk below
    int sI = base + (lane & 31);
    unsigned myk = (sI < N) ? keys[sI] : 0u;

    f32x4 a0 = {0.f,0.f,0.f,0.f}, a1 = {0.f,0.f,0.f,0.f};
    int curk = -1;
    auto flush = [&](void) {
        float* dst = out + ((size_t)curk << 9) + lane * 8;
        #pragma unroll
        for (int e = 0; e < 4; ++e) atomicAdd(dst + e, a0[e]);
        #pragma unroll
        for (int e = 0; e < 4; ++e) atomicAdd(dst + 4 + e, a1[e]);
    };

    int j = 0;
    while (j < n) {
        int b = n - j; if (b > 4) b = 4;
        f32x4 r[4][2];
        int   kk[4];
        #pragma unroll
        for (int t = 0; t < 4; ++t) {       // batch: issue all loads first (MLP)
            if (t < b) {
                unsigned key = __shfl(myk, j + t, 64);
                kk[t] = (int)(key >> 20);
                const f32x4* p = reinterpret_cast<const f32x4*>(
                    nodes + ((size_t)(key & 0xFFFFFu) << 9) + lane * 8);
                r[t][0] = p[0];
                r[t][1] = p[1];
            }
        }
        #pragma unroll
        for (int t = 0; t < 4; ++t) {       // then accumulate with boundary flushes
            if (t < b) {
                if (kk[t] != curk) {
                    if (curk >= 0) flush();
                    curk = kk[t];
                    f32x4 z = {0.f,0.f,0.f,0.f}; a0 = z; a1 = z;
                }
                a0 += r[t][0];
                a1 += r[t][1];
            }
        }
        j += 4;
    }
    if (curk >= 0) flush();
}

extern "C" void kernel_launch(void* const* d_in, const int* in_sizes, int n_in,
                              void* d_out, int out_size, void* d_ws, size_t ws_size,
                              hipStream_t stream) {
    const float* nodes      = (const float*)d_in[0];
    const int*   center_ind = (const int*)d_in[1];
    int K = in_sizes[1];                  // 1024
    int D = out_size / K;                 // 512 (DD)
    int N = in_sizes[0] / D;              // 100000
    (void)D;

    char* ws = (char*)d_ws;
    _Float16* cent16     = (_Float16*)ws;                          // K*DD*2 = 1 MB
    size_t    o          = (size_t)K * DD * 2;
    float*    cent_sq    = (float*)(ws + o);    o += (size_t)K * 4;
    unsigned* assignment = (unsigned*)(ws + o); o += (size_t)N * 4;
    unsigned* counts     = (unsigned*)(ws + o); o += (size_t)K * 4;
    unsigned* cursor     = (unsigned*)(ws + o); o += (size_t)K * 4;
    unsigned* keys       = (unsigned*)(ws + o); o += (size_t)N * 4;
    float*    out        = (float*)d_out;

    hipMemsetAsync(counts, 0, (size_t)K * sizeof(unsigned), stream);
    hipMemsetAsync(out, 0, (size_t)out_size * sizeof(float), stream);

    gather_centers<<<K, 64, 0, stream>>>(nodes, center_ind, cent16, cent_sq, K);
    assign_mfma<<<(N + 63) / 64, 256, 0, stream>>>(nodes, cent16, cent_sq,
                                                   assignment, counts, N, K);
    scan_offsets<<<1, KK, 0, stream>>>(counts, cursor);
    scatter_idx<<<(N + 255) / 256, 256, 0, stream>>>(assignment, cursor, keys, N);
    aggregate3<<<(N + 4 * CHUNK - 1) / (4 * CHUNK), 256, 0, stream>>>(nodes, keys, out, N);
}